// Round 9
// baseline (106.529 us; speedup 1.0000x reference)
//
#include <hip/hip_runtime.h>
#include <hip/hip_bf16.h>

typedef __attribute__((ext_vector_type(8))) short short8;
typedef __attribute__((ext_vector_type(4))) float f32x4;

namespace {
constexpr int Nc  = 2048;   // N
constexpr int NXc = 4096;   // 2N
constexpr int Pc  = 64;
constexpr int Mc  = 4;
constexpr int Dc  = 256;
constexpr int BH  = 16;
constexpr float LOG2E = 1.4426950408889634f;
}

__device__ inline float fexp2(float x) {
#if __has_builtin(__builtin_amdgcn_exp2f)
  return __builtin_amdgcn_exp2f(x);
#else
  return exp2f(x);
#endif
}

__device__ inline unsigned int bfpack(float a, float b) {
  union { __hip_bfloat162 h; unsigned int u; } cv;
  cv.h = __float22bfloat162_rn(make_float2(a, b));
  return cv.u;
}

// Gather pre-pass: Wb[bh][m*256+d][64] = bf16( LOG2E * X[bh][SK[b,m,d]][:] )
// Runs once (~5 us); removes the random-index gather (and its 16x per-(dq,bh)
// redundancy + HBM latency exposure) from the main kernel's critical path.
__global__ __launch_bounds__(256) void prepass_kernel(
    const float* __restrict__ Q, const float* __restrict__ K,
    const int* __restrict__ SK, __hip_bfloat16* __restrict__ Wb)
{
  const int t  = blockIdx.x * 256 + threadIdx.x;
  const int q  = t & 7;
  const int r  = t >> 3;            // 0..16383
  const int bh = r >> 10;
  const int md = r & 1023;
  const int b  = bh >> 3;
  const int idx = SK[b * (Mc * Dc) + md];
  const float* src = (idx < Nc) ? (Q + ((size_t)bh * Nc + idx) * Pc)
                                : (K + ((size_t)bh * Nc + (idx - Nc)) * Pc);
  const f32x4* s4 = (const f32x4*)(src + q * 8);
  f32x4 f0 = s4[0], f1 = s4[1];
  uint4 u;
  u.x = bfpack(f0.x * LOG2E, f0.y * LOG2E);
  u.y = bfpack(f0.z * LOG2E, f0.w * LOG2E);
  u.z = bfpack(f1.x * LOG2E, f1.y * LOG2E);
  u.w = bfpack(f1.z * LOG2E, f1.w * LOG2E);
  *(uint4*)(Wb + (size_t)r * Pc + q * 8) = u;
}

// Main kernel. Block = (nch, dq, bh): 4 waves, 64 d x 256 n.
//
// vs round 8 (fused, ~38.5 us): (1) the W slice is staged from L2-resident
// Wb with fully-coalesced b128 loads instead of random row-gather -- the
// gather's HBM-latency chains sat serially in front of compute with nothing
// to hide them; (2) ALL X global loads are issued BEFORE the single barrier,
// so their latency hides under other-waves' staging + barrier wait (loads
// legally stay in flight across s_barrier; the compiler waits only at the
// post-barrier cvt use); (3) output stores are nontemporal -- OUT is
// write-once/never-read, and 65 MB of streaming writes otherwise thrash the
// 4 MB/XCD L2 (round-2 FETCH=20.5 MB vs 2 MB Wb = ~10x Wb re-fetch).
//
// Compute is round-8's A-reuse: loop dt->m->tt, A-frags ds_read once per
// (dt,m), reused across the wave's 4 n-tiles (8 ds_read_b128 per 4 tiles).
// LDS tile XOR-swizzled (byte ^= (row&7)<<4) -> uniform banks on ds_read.
// Registers: X preload 64 + staging ~20 pre-barrier; b[4]32+acc16+a8+sg4
// post-barrier ~= 100 peak < 128 cap of (256,4) -> no spill/remat hazard.
//
// MFMA: A = W rows (d), B = X rows (n) => C: row = d (q*4+reg), col = n (brow).
__global__ __launch_bounds__(256, 4) void sketch_main(
    const float* __restrict__ Q, const float* __restrict__ K,
    const __hip_bfloat16* __restrict__ Wb,
    const float* __restrict__ SGN, float* __restrict__ OUT)
{
  __shared__ __hip_bfloat16 Ws[Mc * 64 * Pc];   // 32 KB

  const int t    = threadIdx.x;
  const int lane = t & 63;
  const int wv   = t >> 6;
  const int brow = lane & 15;
  const int q    = lane >> 4;
  const int bh   = blockIdx.y;

  // XCD-grouping decode: 4 dq-siblings of one nch on one XCD
  const int bx  = blockIdx.x;           // 0..63
  const int xcd = bx & 7;
  const int rr  = bx >> 3;              // 0..7
  const int nch = xcd * 2 + (rr >> 2);  // 0..15
  const int dq  = rr & 3;               // 0..3
  const int n0  = nch * 256;
  const int d0  = dq * 64;

  char* wsb = (char*)Ws;

  // ---- Stage W slice: Wb rows [m*256 + d0 .. +64) -> swizzled LDS.
  // Coalesced: 4 threads per row, 32B each, linear from L2-resident Wb.
  {
    const int dl = t >> 2;              // 0..63
    const int qt = t & 3;               // 16-elem quarter of the 64-elem row
    const int sw = (dl & 7) << 4;
    const __hip_bfloat16* wsrc =
        Wb + ((size_t)bh * (Mc * Dc) + d0 + dl) * Pc + qt * 16;
    #pragma unroll
    for (int m = 0; m < 4; ++m) {
      uint4 wa = *(const uint4*)(wsrc + (size_t)m * Dc * Pc);
      uint4 wb = *(const uint4*)(wsrc + (size_t)m * Dc * Pc + 8);
      char* rp = wsb + (m * 64 + dl) * 128;
      *(uint4*)(rp + ((qt * 32) ^ sw))      = wa;
      *(uint4*)(rp + ((qt * 32 + 16) ^ sw)) = wb;
    }
  }

  // ---- Issue ALL X loads for this wave's 4 n-tiles BEFORE the barrier.
  const float* xr = ((n0 < Nc) ? (Q + ((size_t)bh * Nc + n0) * Pc)
                               : (K + ((size_t)bh * Nc + (n0 - Nc)) * Pc))
                    + (size_t)(wv * 64 + brow) * Pc + q * 8;
  f32x4 xv[16];
  #pragma unroll
  for (int tt = 0; tt < 4; ++tt) {
    const float* xp = xr + (size_t)tt * 16 * Pc;
    xv[tt * 4 + 0] = *(const f32x4*)(xp);
    xv[tt * 4 + 1] = *(const f32x4*)(xp + 4);
    xv[tt * 4 + 2] = *(const f32x4*)(xp + 32);
    xv[tt * 4 + 3] = *(const f32x4*)(xp + 36);
  }

  __syncthreads();   // the only barrier; X loads remain in flight across it

  // ---- Convert X -> bf16 B-fragments (waits on the loads here, not earlier)
  short8 b0[4], b1[4];
  #pragma unroll
  for (int tt = 0; tt < 4; ++tt) {
    union { short8 s; uint4 u; } c0, c1;
    f32x4 x0 = xv[tt * 4 + 0], x1 = xv[tt * 4 + 1];
    f32x4 x2 = xv[tt * 4 + 2], x3 = xv[tt * 4 + 3];
    c0.u.x = bfpack(x0.x, x0.y); c0.u.y = bfpack(x0.z, x0.w);
    c0.u.z = bfpack(x1.x, x1.y); c0.u.w = bfpack(x1.z, x1.w);
    c1.u.x = bfpack(x2.x, x2.y); c1.u.y = bfpack(x2.z, x2.w);
    c1.u.z = bfpack(x3.x, x3.y); c1.u.w = bfpack(x3.z, x3.w);
    b0[tt] = c0.s; b1[tt] = c1.s;
  }

  const int swr = (brow & 7) << 4;   // row&7 == brow&7 (dt*16, m*64 mult of 8)
  float* obase = OUT + ((size_t)bh * NXc + n0 + wv * 64 + brow) * Dc + d0 + q * 4;

  #pragma unroll
  for (int dt = 0; dt < 4; ++dt) {
    f32x4 acc[4];
    #pragma unroll
    for (int tt = 0; tt < 4; ++tt) acc[tt] = (f32x4){0.f, 0.f, 0.f, 0.f};

    #pragma unroll
    for (int m = 0; m < 4; ++m) {
      const char* ap = wsb + (m * 64 + dt * 16 + brow) * 128;
      short8 a0 = *(const short8*)(ap + ((q * 16) ^ swr));
      short8 a1 = *(const short8*)(ap + ((64 + q * 16) ^ swr));
      const f32x4 sg = *(const f32x4*)(SGN + m * Dc + d0 + dt * 16 + q * 4);
      #pragma unroll
      for (int tt = 0; tt < 4; ++tt) {
        f32x4 c = {0.f, 0.f, 0.f, 0.f};
        c = __builtin_amdgcn_mfma_f32_16x16x32_bf16(a0, b0[tt], c, 0, 0, 0);
        c = __builtin_amdgcn_mfma_f32_16x16x32_bf16(a1, b1[tt], c, 0, 0, 0);
        acc[tt].x = fmaf(sg.x, fexp2(c.x), acc[tt].x);
        acc[tt].y = fmaf(sg.y, fexp2(c.y), acc[tt].y);
        acc[tt].z = fmaf(sg.z, fexp2(c.z), acc[tt].z);
        acc[tt].w = fmaf(sg.w, fexp2(c.w), acc[tt].w);
      }
    }

    // n = n0 + (wv*4+tt)*16 + brow (col), d = d0 + dt*16 + q*4 + reg
    // nontemporal: OUT is write-once, never re-read -> don't thrash L2.
    #pragma unroll
    for (int tt = 0; tt < 4; ++tt) {
      __builtin_nontemporal_store(
          acc[tt], (f32x4*)(obase + (size_t)tt * 16 * Dc + dt * 16));
    }
  }
}

extern "C" void kernel_launch(void* const* d_in, const int* in_sizes, int n_in,
                              void* d_out, int out_size, void* d_ws, size_t ws_size,
                              hipStream_t stream) {
  (void)in_sizes; (void)n_in; (void)out_size; (void)ws_size;
  const float* Q   = (const float*)d_in[0];
  const float* K   = (const float*)d_in[1];
  const int*   SK  = (const int*)d_in[2];
  const float* SGN = (const float*)d_in[3];
  float* OUT = (float*)d_out;

  __hip_bfloat16* Wb = (__hip_bfloat16*)d_ws;  // 2 MiB

  prepass_kernel<<<dim3(512), dim3(256), 0, stream>>>(Q, K, SK, Wb);
  sketch_main<<<dim3(64, BH), dim3(256), 0, stream>>>(Q, K, Wb, SGN, OUT);
}